// Round 10
// baseline (806.604 us; speedup 1.0000x reference)
//
#include <hip/hip_runtime.h>

typedef unsigned short ushort_t;
typedef unsigned int uint_t;
typedef __attribute__((ext_vector_type(8))) short short8;
typedef __attribute__((ext_vector_type(8))) _Float16 half8;
typedef __attribute__((ext_vector_type(4))) _Float16 half4;
typedef __attribute__((ext_vector_type(4))) float float4v;

#define MFMA_BF16(a, b, c) __builtin_amdgcn_mfma_f32_16x16x32_bf16((a), (b), (c), 0, 0, 0)
#define MFMA_F16(a, b, c) __builtin_amdgcn_mfma_f32_16x16x32_f16((a), (b), (c), 0, 0, 0)

#define NQ 8192
#define DIM 256
#define DV 512

// round-to-nearest-even f32 -> bf16 (raw bits)
__device__ __forceinline__ ushort_t f2bf(float x) {
  union { float f; uint_t u; } v; v.f = x;
  return (ushort_t)((v.u + 0x7fffu + ((v.u >> 16) & 1u)) >> 16);
}

__device__ __forceinline__ half8 cvt8h(const float* p) {
  float4v a = *(const float4v*)p;
  float4v b = *(const float4v*)(p + 4);
  half8 r;
  r[0] = (_Float16)a[0]; r[1] = (_Float16)a[1];
  r[2] = (_Float16)a[2]; r[3] = (_Float16)a[3];
  r[4] = (_Float16)b[0]; r[5] = (_Float16)b[1];
  r[6] = (_Float16)b[2]; r[7] = (_Float16)b[3];
  return r;
}

__device__ __forceinline__ half8 as_h8(short8 s) {
  union { short8 s; half8 h; } u; u.s = s; return u.h;
}

// async global->LDS, 16B per lane; lds dest is wave-uniform base (HW adds lane*16)
__device__ __forceinline__ void load_lds_16(const void* g, void* l) {
  __builtin_amdgcn_global_load_lds(
      (const __attribute__((address_space(1))) uint_t*)g,
      (__attribute__((address_space(3))) uint_t*)l, 16, 0, 0);
}

// raw barriers (avoid __syncthreads' forced full drain where not needed)
__device__ __forceinline__ void barrier_vm0_lgkm0() {
  asm volatile("s_waitcnt vmcnt(0) lgkmcnt(0)\ns_barrier" ::: "memory");
}
__device__ __forceinline__ void barrier_lgkm0() {
  asm volatile("s_waitcnt lgkmcnt(0)\ns_barrier" ::: "memory");
}

// ---------------- fused pre: proj (blocks 0..1023) + Vt transpose (1024..2047) ----
__global__ __launch_bounds__(256, 2) void pre_kernel(
    const float* __restrict__ img, const float* __restrict__ text,
    const float* __restrict__ Wq, const float* __restrict__ Wk,
    _Float16* __restrict__ Qh, _Float16* __restrict__ Kh,
    ushort_t* __restrict__ Vt) {
  __shared__ float tile[64][65];
  const int bid = blockIdx.x;
  const int tid = threadIdx.x;
  if (bid < 1024) {
    const int bx = bid & 127;
    const int by = (bid >> 7) & 3;
    const int bz = bid >> 9;
    const int lane = tid & 63;
    const int wv = tid >> 6;
    const int l16 = lane & 15;
    const int quad = lane >> 4;
    const float* A = bz ? text : img;
    const float* W = bz ? Wk : Wq;
    _Float16* C = bz ? Kh : Qh;
    const int row = bx * 64 + wv * 16 + l16;
    const int colbase = by * 64;

    float4v acc[4];
#pragma unroll
    for (int c = 0; c < 4; ++c) acc[c] = (float4v){0.f, 0.f, 0.f, 0.f};
#pragma unroll
    for (int f = 0; f < 8; ++f) {
      const int k0 = f * 32 + quad * 8;
      half8 af = cvt8h(A + (size_t)row * DIM + k0);
#pragma unroll
      for (int c = 0; c < 4; ++c) {
        half8 bfr = cvt8h(W + (size_t)(colbase + c * 16 + l16) * DIM + k0);
        acc[c] = MFMA_F16(af, bfr, acc[c]);
      }
    }
    const int rbase = bx * 64 + wv * 16 + quad * 4;
#pragma unroll
    for (int c = 0; c < 4; ++c)
#pragma unroll
      for (int r = 0; r < 4; ++r)
        C[(size_t)(rbase + r) * DIM + colbase + c * 16 + l16] = (_Float16)acc[c][r];
  } else {
    const int vb = bid - 1024;
    const int n0 = (vb & 127) * 64;
    const int c0 = (vb >> 7) * 64;
    const float* src = (c0 < 256) ? img : text;
    const int cc0 = (c0 < 256) ? c0 : (c0 - 256);
#pragma unroll
    for (int i = 0; i < 4; ++i) {
      const int r = i * 16 + (tid >> 4);
      const int c = (tid & 15) * 4;
      *(float4v*)&tile[r][c] = *(const float4v*)(src + (size_t)(n0 + r) * DIM + cc0 + c);
    }
    __syncthreads();
    const int c = tid >> 2;
    const int seg = tid & 3;
    ushort_t tmp[16];
#pragma unroll
    for (int t = 0; t < 16; ++t) tmp[t] = f2bf(tile[seg * 16 + t][c]);
    ushort_t* dst = Vt + (size_t)(c0 + c) * NQ + n0 + seg * 16;
    *(short8*)dst = *(short8*)&tmp[0];
    *(short8*)(dst + 8) = *(short8*)&tmp[8];
  }
}

// stage K tile (32 keys x 512B = 1024 chunks) with 512 threads
__device__ __forceinline__ void stage_K(const _Float16* __restrict__ Kh, int k0,
                                        ushort_t* dst, int tid, int wv) {
#pragma unroll
  for (int i = 0; i < 2; ++i) {
    const int chunk = i * 512 + tid;
    const int n = chunk >> 5;
    const int cs = (chunk & 31) ^ (n & 7);
    load_lds_16(Kh + (size_t)(k0 + n) * DIM + cs * 8,
                (char*)dst + (i * 512 + wv * 64) * 16);
  }
}
// stage V tile (512 vrows x 64B = 2048 chunks) with 512 threads
__device__ __forceinline__ void stage_V(const ushort_t* __restrict__ Vt, int k0,
                                        ushort_t* dst, int tid, int wv) {
#pragma unroll
  for (int i = 0; i < 4; ++i) {
    const int chunk = i * 512 + tid;
    const int vrow = chunk >> 2;
    const int dc = (chunk & 3) ^ ((vrow >> 1) & 3);
    load_lds_16(Vt + (size_t)vrow * NQ + k0 + dc * 8,
                (char*)dst + (i * 512 + wv * 64) * 16);
  }
}

// ---------------- fused attention v4: 512-thread blocks, 4 waves/SIMD ----------------
// Grid = 128 qtiles * ks (512 blocks). split = id&(ks-1): constant per XCD.
// 8 waves: S role = (qblk = wv&3 [16 q-rows], kh = wv>>2 [16-key half]);
// PV role = vcols [wv*64, wv*64+64) for all 64 q. Denom = ones-MFMA on waves 0-3.
// Skewed pipeline per tile t: B1(vm0+lgkm0) -> prefetch K(t+1) -> PV(t-1) || S(t)
//                             B2(lgkm0) -> stage V(t) -> exp -> P(t) dbuf.
// LDS (ushorts): K dbuf @0,@8192; V @16384 (32KB); P dbuf @32768,@34816. 72KB.
__global__ __launch_bounds__(512, 4) void attn_kernel(
    const _Float16* __restrict__ Qh, const _Float16* __restrict__ Kh,
    const ushort_t* __restrict__ Vt, _Float16* __restrict__ pacc,
    float* __restrict__ pdenom, int kps, int ks) {
  extern __shared__ __align__(16) ushort_t smem[];
  ushort_t* ldsV = smem + 16384;

  const int tid = threadIdx.x;
  const int lane = tid & 63;
  const int wv = tid >> 6;       // 0..7
  const int l16 = lane & 15;
  const int quad = (lane >> 4) & 3;
  const int qblk = wv & 3;       // S-phase q-block
  const int kh = wv >> 2;        // S-phase key-half
  const int id = blockIdx.x;
  const int split = id & (ks - 1);
  const int qtile = id / ks;     // 0..127
  const int kbeg = split * kps;
  const int sw2 = (l16 >> 1) & 3;
  const int swk = l16 & 7;

  const short8 ones = {0x3F80, 0x3F80, 0x3F80, 0x3F80, 0x3F80, 0x3F80, 0x3F80, 0x3F80};

  // Q fragments for this wave's 16 S-rows (qblk): A-layout m=l16, k=quad*8+j
  short8 qf[8];
  {
    const _Float16* qptr = Qh + (size_t)(qtile * 64 + qblk * 16 + l16) * DIM;
#pragma unroll
    for (int f = 0; f < 8; ++f)
      qf[f] = *(const short8*)(qptr + f * 32 + quad * 8);
  }

  // acc[m][c]: q-block m (16 rows), vcol tile c within wave's 64 cols
  float4v acc[4][4];
#pragma unroll
  for (int m = 0; m < 4; ++m)
#pragma unroll
    for (int c = 0; c < 4; ++c) acc[m][c] = (float4v){0.f, 0.f, 0.f, 0.f};
  float4v dden = (float4v){0.f, 0.f, 0.f, 0.f};  // denom acc (waves 0-3, m=wv)

  const int ntiles = kps >> 5;

  // prologue: stage K(0) and V(0)
  stage_K(Kh, kbeg, smem, tid, wv);
  stage_V(Vt, kbeg, ldsV, tid, wv);

  for (int t = 0; t < ntiles; ++t) {
    const ushort_t* Kt = smem + (t & 1) * 8192;
    // B1: K(t)+V staged (vm0); P(t-1) writes visible (lgkm0)
    barrier_vm0_lgkm0();
    if (t + 1 < ntiles)
      stage_K(Kh, kbeg + (t + 1) * 32, smem + ((t + 1) & 1) * 8192, tid, wv);

    // PV(t-1): wave owns vcols [wv*64, wv*64+64) for all 64 q-rows
    if (t > 0) {
      const ushort_t* Pprev = smem + 32768 + ((t - 1) & 1) * 2048;
      short8 pa[4];
#pragma unroll
      for (int m = 0; m < 4; ++m)
        pa[m] = *(const short8*)(Pprev + (m * 16 + l16) * 32 + (quad ^ sw2) * 8);
#pragma unroll
      for (int c = 0; c < 4; ++c) {
        const int vcol = (wv * 4 + c) * 16 + l16;
        short8 vb = *(const short8*)(ldsV + vcol * 32 + (quad ^ sw2) * 8);
#pragma unroll
        for (int m = 0; m < 4; ++m)
          acc[m][c] = MFMA_BF16(pa[m], vb, acc[m][c]);
      }
      if (wv < 4) dden = MFMA_BF16(pa[wv], ones, dden);  // row-sums of rounded P
    }

    // S(t): this wave's 16 q (qblk) x 16 keys (half kh)
    float4v s = (float4v){0.f, 0.f, 0.f, 0.f};
#pragma unroll
    for (int f = 0; f < 8; ++f) {
      const int cs = ((f * 4 + quad) ^ swk) * 8;
      short8 kb = *(const short8*)(Kt + (kh * 16 + l16) * DIM + cs);
      s = MFMA_F16(as_h8(qf[f]), as_h8(kb), s);
    }

    // B2: all PV(t-1)/S(t) LDS reads retired -> V buffer free to restage
    barrier_lgkm0();
    if (t >= 1) stage_V(Vt, kbeg + t * 32, ldsV, tid, wv);

    // exp + write P(t) (bf16) into its dbuf slot
    ushort_t* Pcur = smem + 32768 + (t & 1) * 2048;
#pragma unroll
    for (int r = 0; r < 4; ++r) {
      const ushort_t p = f2bf(__expf(s[r]));
      const int rb = qblk * 16 + quad * 4 + r;
      const int kc = kh * 2 + (l16 >> 3);               // key chunk 0..3
      const int pos = kc ^ ((rb >> 1) & 3);
      Pcur[rb * 32 + pos * 8 + (l16 & 7)] = p;
    }
  }

  // epilogue: final PV(ntiles-1)
  barrier_vm0_lgkm0();
  {
    const ushort_t* Pprev = smem + 32768 + ((ntiles - 1) & 1) * 2048;
    short8 pa[4];
#pragma unroll
    for (int m = 0; m < 4; ++m)
      pa[m] = *(const short8*)(Pprev + (m * 16 + l16) * 32 + (quad ^ sw2) * 8);
#pragma unroll
    for (int c = 0; c < 4; ++c) {
      const int vcol = (wv * 4 + c) * 16 + l16;
      short8 vb = *(const short8*)(ldsV + vcol * 32 + (quad ^ sw2) * 8);
#pragma unroll
      for (int m = 0; m < 4; ++m)
        acc[m][c] = MFMA_BF16(pa[m], vb, acc[m][c]);
    }
    if (wv < 4) dden = MFMA_BF16(pa[wv], ones, dden);
  }

  // denom exchange via LDS (K area, dead), store normalized fp16 partials
  barrier_lgkm0();
  float* ldsD = (float*)smem;  // 64 floats
  if (wv < 4 && l16 == 0) {
#pragma unroll
    for (int r = 0; r < 4; ++r)
      ldsD[wv * 16 + quad * 4 + r] = dden[r];
  }
  barrier_lgkm0();

  _Float16* pout = pacc + (size_t)split * ((size_t)NQ * DV);
#pragma unroll
  for (int m = 0; m < 4; ++m) {
    float invd[4];
#pragma unroll
    for (int r = 0; r < 4; ++r) invd[r] = 1.0f / ldsD[m * 16 + quad * 4 + r];
    const int rowbase = qtile * 64 + m * 16 + quad * 4;
#pragma unroll
    for (int c = 0; c < 4; ++c) {
      const int col = (wv * 4 + c) * 16 + l16;
#pragma unroll
      for (int r = 0; r < 4; ++r)
        pout[(size_t)(rowbase + r) * DV + col] = (_Float16)(acc[m][c][r] * invd[r]);
    }
  }
  if (wv < 4 && l16 == 0) {
    const int rowbase = qtile * 64 + wv * 16 + quad * 4;
#pragma unroll
    for (int r = 0; r < 4; ++r)
      pdenom[split * NQ + rowbase + r] = dden[r];
  }
}

// ---------------- combine: out = sum_i d_i*x_i / (16 * sum_i d_i) ----------------
__global__ __launch_bounds__(256) void combine_kernel(
    const _Float16* __restrict__ pacc, const float* __restrict__ pdenom,
    float* __restrict__ out, int ks) {
  const int idx = blockIdx.x * 256 + threadIdx.x;
  const int n = idx >> 7;
  const int c4 = (idx & 127) << 2;
  float4v s = (float4v){0.f, 0.f, 0.f, 0.f};
  float dsum = 0.f;
  for (int sp = 0; sp < ks; ++sp) {
    const float d = pdenom[sp * NQ + n];
    half4 x = *(const half4*)(pacc + (size_t)sp * ((size_t)NQ * DV) + (size_t)n * DV + c4);
    s[0] += d * (float)x[0];
    s[1] += d * (float)x[1];
    s[2] += d * (float)x[2];
    s[3] += d * (float)x[3];
    dsum += d;
  }
  const float scale = 1.0f / (16.0f * dsum);  // 1/sqrt(256) applied post-softmax
  s *= scale;
  float* dst = (c4 < 256) ? (out + (size_t)n * DIM + c4)
                          : (out + (size_t)NQ * DIM + (size_t)n * DIM + (c4 - 256));
  *(float4v*)dst = s;
}

extern "C" void kernel_launch(void* const* d_in, const int* in_sizes, int n_in,
                              void* d_out, int out_size, void* d_ws, size_t ws_size,
                              hipStream_t stream) {
  const float* img = (const float*)d_in[0];
  const float* text = (const float*)d_in[1];
  const float* Wq = (const float*)d_in[2];
  const float* Wk = (const float*)d_in[3];
  float* out = (float*)d_out;
  char* ws = (char*)d_ws;

  _Float16* Qh = (_Float16*)ws;                        // 4 MiB
  _Float16* Kh = (_Float16*)(ws + ((size_t)4 << 20));  // 4 MiB
  ushort_t* Vt = (ushort_t*)(ws + ((size_t)8 << 20));  // 8 MiB
  const size_t accsz = (size_t)NQ * DV * sizeof(_Float16);  // 8 MiB per split
  const size_t base = (size_t)16 << 20;

  int ks = 4;
  if (ws_size < base + 4 * (accsz + NQ * sizeof(float))) ks = 2;
  _Float16* pacc = (_Float16*)(ws + base);
  float* pdenom = (float*)(ws + base + (size_t)ks * accsz);

  hipLaunchKernelGGL(pre_kernel, dim3(2048), dim3(256), 0, stream,
                     img, text, Wq, Wk, Qh, Kh, Vt);
  hipLaunchKernelGGL(attn_kernel, dim3(128 * ks), dim3(512),
                     36864 * sizeof(ushort_t), stream,
                     Qh, Kh, Vt, pacc, pdenom, NQ / ks, ks);
  hipLaunchKernelGGL(combine_kernel, dim3((NQ * DV / 4) / 256), dim3(256), 0, stream,
                     pacc, pdenom, out, ks);
}

// Round 11
// 415.507 us; speedup vs baseline: 1.9413x; 1.9413x over previous
//
#include <hip/hip_runtime.h>

typedef unsigned short ushort_t;
typedef unsigned int uint_t;
typedef __attribute__((ext_vector_type(8))) short short8;
typedef __attribute__((ext_vector_type(8))) _Float16 half8;
typedef __attribute__((ext_vector_type(4))) _Float16 half4;
typedef __attribute__((ext_vector_type(4))) float float4v;

#define MFMA_BF16(a, b, c) __builtin_amdgcn_mfma_f32_16x16x32_bf16((a), (b), (c), 0, 0, 0)
#define MFMA_F16(a, b, c) __builtin_amdgcn_mfma_f32_16x16x32_f16((a), (b), (c), 0, 0, 0)

#define NQ 8192
#define DIM 256
#define DV 512

// round-to-nearest-even f32 -> bf16 (raw bits)
__device__ __forceinline__ ushort_t f2bf(float x) {
  union { float f; uint_t u; } v; v.f = x;
  return (ushort_t)((v.u + 0x7fffu + ((v.u >> 16) & 1u)) >> 16);
}

__device__ __forceinline__ half8 cvt8h(const float* p) {
  float4v a = *(const float4v*)p;
  float4v b = *(const float4v*)(p + 4);
  half8 r;
  r[0] = (_Float16)a[0]; r[1] = (_Float16)a[1];
  r[2] = (_Float16)a[2]; r[3] = (_Float16)a[3];
  r[4] = (_Float16)b[0]; r[5] = (_Float16)b[1];
  r[6] = (_Float16)b[2]; r[7] = (_Float16)b[3];
  return r;
}

__device__ __forceinline__ half8 as_h8(short8 s) {
  union { short8 s; half8 h; } u; u.s = s; return u.h;
}

// async global->LDS, 16B per lane; lds dest is wave-uniform base (HW adds lane*16)
__device__ __forceinline__ void load_lds_16(const void* g, void* l) {
  __builtin_amdgcn_global_load_lds(
      (const __attribute__((address_space(1))) uint_t*)g,
      (__attribute__((address_space(3))) uint_t*)l, 16, 0, 0);
}

// raw barriers (avoid __syncthreads' forced full drain where not needed)
__device__ __forceinline__ void barrier_vm0_lgkm0() {
  asm volatile("s_waitcnt vmcnt(0) lgkmcnt(0)\ns_barrier" ::: "memory");
}
__device__ __forceinline__ void barrier_lgkm0() {
  asm volatile("s_waitcnt lgkmcnt(0)\ns_barrier" ::: "memory");
}

// ---------------- fused pre: proj (blocks 0..1023) + Vt transpose (1024..2047) ----
__global__ __launch_bounds__(256, 2) void pre_kernel(
    const float* __restrict__ img, const float* __restrict__ text,
    const float* __restrict__ Wq, const float* __restrict__ Wk,
    _Float16* __restrict__ Qh, _Float16* __restrict__ Kh,
    ushort_t* __restrict__ Vt) {
  __shared__ float tile[64][65];
  const int bid = blockIdx.x;
  const int tid = threadIdx.x;
  if (bid < 1024) {
    const int bx = bid & 127;
    const int by = (bid >> 7) & 3;
    const int bz = bid >> 9;
    const int lane = tid & 63;
    const int wv = tid >> 6;
    const int l16 = lane & 15;
    const int quad = lane >> 4;
    const float* A = bz ? text : img;
    const float* W = bz ? Wk : Wq;
    _Float16* C = bz ? Kh : Qh;
    const int row = bx * 64 + wv * 16 + l16;
    const int colbase = by * 64;

    float4v acc[4];
#pragma unroll
    for (int c = 0; c < 4; ++c) acc[c] = (float4v){0.f, 0.f, 0.f, 0.f};
#pragma unroll
    for (int f = 0; f < 8; ++f) {
      const int k0 = f * 32 + quad * 8;
      half8 af = cvt8h(A + (size_t)row * DIM + k0);
#pragma unroll
      for (int c = 0; c < 4; ++c) {
        half8 bfr = cvt8h(W + (size_t)(colbase + c * 16 + l16) * DIM + k0);
        acc[c] = MFMA_F16(af, bfr, acc[c]);
      }
    }
    const int rbase = bx * 64 + wv * 16 + quad * 4;
#pragma unroll
    for (int c = 0; c < 4; ++c)
#pragma unroll
      for (int r = 0; r < 4; ++r)
        C[(size_t)(rbase + r) * DIM + colbase + c * 16 + l16] = (_Float16)acc[c][r];
  } else {
    const int vb = bid - 1024;
    const int n0 = (vb & 127) * 64;
    const int c0 = (vb >> 7) * 64;
    const float* src = (c0 < 256) ? img : text;
    const int cc0 = (c0 < 256) ? c0 : (c0 - 256);
#pragma unroll
    for (int i = 0; i < 4; ++i) {
      const int r = i * 16 + (tid >> 4);
      const int c = (tid & 15) * 4;
      *(float4v*)&tile[r][c] = *(const float4v*)(src + (size_t)(n0 + r) * DIM + cc0 + c);
    }
    __syncthreads();
    const int c = tid >> 2;
    const int seg = tid & 3;
    ushort_t tmp[16];
#pragma unroll
    for (int t = 0; t < 16; ++t) tmp[t] = f2bf(tile[seg * 16 + t][c]);
    ushort_t* dst = Vt + (size_t)(c0 + c) * NQ + n0 + seg * 16;
    *(short8*)dst = *(short8*)&tmp[0];
    *(short8*)(dst + 8) = *(short8*)&tmp[8];
  }
}

// stage K tile (32 keys x 512B = 1024 chunks) with 256 threads; XOR src swizzle
__device__ __forceinline__ void stage_K(const _Float16* __restrict__ Kh, int k0,
                                        ushort_t* dst, int tid, int wv) {
#pragma unroll
  for (int i = 0; i < 4; ++i) {
    const int chunk = i * 256 + tid;
    const int n = chunk >> 5;
    const int cs = (chunk & 31) ^ (n & 7);
    load_lds_16(Kh + (size_t)(k0 + n) * DIM + cs * 8,
                (char*)dst + (i * 256 + wv * 64) * 16);
  }
}

// ---------------- fused attention v5: V global->reg direct, 1 barrier/tile ----------
// Grid = 128 qtiles * ks. split = id&(ks-1): constant per XCD (L2-local split).
// 64 q/block, 4 waves. Per tile t (single barrier B1 = vm0+lgkm0):
//   B1 -> prefetch K(t+1) -> PV(t-1) [P from LDS dbuf, V from regs] + denom MFMA
//      -> issue V(t) reg loads -> S(t) [K from LDS] -> exp -> write P(t) dbuf.
// B2 removed: P-dbuf slot t&1 was last read at PV(t-2) (retired before this B1);
// K slot (t+1)&1 last read at S(t-1) (retired before this B1).
// LDS (ushorts): K dbuf @0,@8192 (16KB each); P dbuf @16384,@18432 (4KB each). 40KB.
__global__ __launch_bounds__(256, 2) void attn_kernel(
    const _Float16* __restrict__ Qh, const _Float16* __restrict__ Kh,
    const ushort_t* __restrict__ Vt, _Float16* __restrict__ pacc,
    float* __restrict__ pdenom, int kps, int ks) {
  extern __shared__ __align__(16) ushort_t smem[];

  const int tid = threadIdx.x;
  const int lane = tid & 63;
  const int wv = tid >> 6;
  const int l16 = lane & 15;
  const int quad = lane >> 4;
  const int id = blockIdx.x;
  const int split = id & (ks - 1);
  const int qtile = id / ks;  // 0..127
  const int kbeg = split * kps;
  const int sw2 = (l16 >> 1) & 3;
  const int swk = l16 & 7;

  const short8 ones = {0x3F80, 0x3F80, 0x3F80, 0x3F80, 0x3F80, 0x3F80, 0x3F80, 0x3F80};

  // Q fragments for this wave's 16 S-rows: A-layout m=l16, k=quad*8+j
  short8 qf[8];
  {
    const _Float16* qptr = Qh + (size_t)(qtile * 64 + wv * 16 + l16) * DIM;
#pragma unroll
    for (int f = 0; f < 8; ++f)
      qf[f] = *(const short8*)(qptr + f * 32 + quad * 8);
  }

  float4v acc[4][8];
#pragma unroll
  for (int m = 0; m < 4; ++m)
#pragma unroll
    for (int c = 0; c < 8; ++c) acc[m][c] = (float4v){0.f, 0.f, 0.f, 0.f};
  float4v dden = (float4v){0.f, 0.f, 0.f, 0.f};  // row-sums of rounded P (q-block wv)

  const int ntiles = kps >> 5;

  // prologue: stage K(0), load V(0) fragments into registers
  stage_K(Kh, kbeg, smem, tid, wv);
  short8 vreg[8];
#pragma unroll
  for (int c = 0; c < 8; ++c) {
    const int vcol = (wv * 8 + c) * 16 + l16;
    vreg[c] = *(const short8*)(Vt + (size_t)vcol * NQ + kbeg + quad * 8);
  }

  for (int t = 0; t < ntiles; ++t) {
    const ushort_t* Kt = smem + (t & 1) * 8192;
    // B1: K(t) in LDS + V(t) in regs (vm0); P(t-1) writes visible (lgkm0)
    barrier_vm0_lgkm0();
    if (t + 1 < ntiles)
      stage_K(Kh, kbeg + (t + 1) * 32, smem + ((t + 1) & 1) * 8192, tid, wv);

    // PV(t-1): wave owns vcols [wv*128, wv*128+128) for all 64 q-rows
    if (t > 0) {
      const ushort_t* Pprev = smem + 16384 + ((t - 1) & 1) * 2048;
      short8 pa[4];
#pragma unroll
      for (int m = 0; m < 4; ++m)
        pa[m] = *(const short8*)(Pprev + (m * 16 + l16) * 32 + (quad ^ sw2) * 8);
#pragma unroll
      for (int c = 0; c < 8; ++c) {
#pragma unroll
        for (int m = 0; m < 4; ++m)
          acc[m][c] = MFMA_BF16(pa[m], vreg[c], acc[m][c]);
      }
      dden = MFMA_BF16(pa[wv], ones, dden);  // denom via ones-MFMA (q-block wv)
      // issue V(t) reg loads (consumed at PV(t), iter t+1; covered by next B1 vm0)
#pragma unroll
      for (int c = 0; c < 8; ++c) {
        const int vcol = (wv * 8 + c) * 16 + l16;
        vreg[c] = *(const short8*)(Vt + (size_t)vcol * NQ + (kbeg + t * 32) + quad * 8);
      }
    }

    // S(t) = Q K^T (this wave's 16 q-rows x 32 keys)
    float4v s0 = (float4v){0.f, 0.f, 0.f, 0.f};
    float4v s1 = (float4v){0.f, 0.f, 0.f, 0.f};
#pragma unroll
    for (int f = 0; f < 8; ++f) {
      const int cs = ((f * 4 + quad) ^ swk) * 8;
      short8 kb0 = *(const short8*)(Kt + l16 * DIM + cs);
      short8 kb1 = *(const short8*)(Kt + (l16 + 16) * DIM + cs);
      s0 = MFMA_F16(as_h8(qf[f]), as_h8(kb0), s0);
      s1 = MFMA_F16(as_h8(qf[f]), as_h8(kb1), s1);
    }

    // exp + write P(t) (bf16) into its dbuf slot (no barrier needed: see header)
    ushort_t* Pcur = smem + 16384 + (t & 1) * 2048;
#pragma unroll
    for (int r = 0; r < 4; ++r) {
      const ushort_t p0 = f2bf(__expf(s0[r]));
      const ushort_t p1 = f2bf(__expf(s1[r]));
      const int rb = wv * 16 + quad * 4 + r;
      const int swp = (rb >> 1) & 3;
      Pcur[rb * 32 + ((l16 >> 3) ^ swp) * 8 + (l16 & 7)] = p0;
      Pcur[rb * 32 + ((2 + (l16 >> 3)) ^ swp) * 8 + (l16 & 7)] = p1;
    }
  }

  // epilogue: final PV(ntiles-1)
  barrier_vm0_lgkm0();
  {
    const ushort_t* Pprev = smem + 16384 + ((ntiles - 1) & 1) * 2048;
    short8 pa[4];
#pragma unroll
    for (int m = 0; m < 4; ++m)
      pa[m] = *(const short8*)(Pprev + (m * 16 + l16) * 32 + (quad ^ sw2) * 8);
#pragma unroll
    for (int c = 0; c < 8; ++c) {
#pragma unroll
      for (int m = 0; m < 4; ++m)
        acc[m][c] = MFMA_BF16(pa[m], vreg[c], acc[m][c]);
    }
    dden = MFMA_BF16(pa[wv], ones, dden);
  }

  // denom exchange via LDS (K area, dead), store normalized fp16 partials
  barrier_lgkm0();
  float* ldsD = (float*)smem;  // 64 floats
  if (l16 == 0) {
#pragma unroll
    for (int r = 0; r < 4; ++r)
      ldsD[wv * 16 + quad * 4 + r] = dden[r];
  }
  barrier_lgkm0();

  _Float16* pout = pacc + (size_t)split * ((size_t)NQ * DV);
#pragma unroll
  for (int m = 0; m < 4; ++m) {
    float invd[4];
#pragma unroll
    for (int r = 0; r < 4; ++r) invd[r] = 1.0f / ldsD[m * 16 + quad * 4 + r];
    const int rowbase = qtile * 64 + m * 16 + quad * 4;
#pragma unroll
    for (int c = 0; c < 8; ++c) {
      const int col = (wv * 8 + c) * 16 + l16;
#pragma unroll
      for (int r = 0; r < 4; ++r)
        pout[(size_t)(rowbase + r) * DV + col] = (_Float16)(acc[m][c][r] * invd[r]);
    }
  }
  if (l16 == 0) {
    const int rowbase = qtile * 64 + wv * 16 + quad * 4;
#pragma unroll
    for (int r = 0; r < 4; ++r)
      pdenom[split * NQ + rowbase + r] = dden[r];
  }
}

// ---------------- combine: out = sum_i d_i*x_i / (16 * sum_i d_i) ----------------
__global__ __launch_bounds__(256) void combine_kernel(
    const _Float16* __restrict__ pacc, const float* __restrict__ pdenom,
    float* __restrict__ out, int ks) {
  const int idx = blockIdx.x * 256 + threadIdx.x;
  const int n = idx >> 7;
  const int c4 = (idx & 127) << 2;
  float4v s = (float4v){0.f, 0.f, 0.f, 0.f};
  float dsum = 0.f;
  for (int sp = 0; sp < ks; ++sp) {
    const float d = pdenom[sp * NQ + n];
    half4 x = *(const half4*)(pacc + (size_t)sp * ((size_t)NQ * DV) + (size_t)n * DV + c4);
    s[0] += d * (float)x[0];
    s[1] += d * (float)x[1];
    s[2] += d * (float)x[2];
    s[3] += d * (float)x[3];
    dsum += d;
  }
  const float scale = 1.0f / (16.0f * dsum);  // 1/sqrt(256) applied post-softmax
  s *= scale;
  float* dst = (c4 < 256) ? (out + (size_t)n * DIM + c4)
                          : (out + (size_t)NQ * DIM + (size_t)n * DIM + (c4 - 256));
  *(float4v*)dst = s;
}

extern "C" void kernel_launch(void* const* d_in, const int* in_sizes, int n_in,
                              void* d_out, int out_size, void* d_ws, size_t ws_size,
                              hipStream_t stream) {
  const float* img = (const float*)d_in[0];
  const float* text = (const float*)d_in[1];
  const float* Wq = (const float*)d_in[2];
  const float* Wk = (const float*)d_in[3];
  float* out = (float*)d_out;
  char* ws = (char*)d_ws;

  _Float16* Qh = (_Float16*)ws;                        // 4 MiB
  _Float16* Kh = (_Float16*)(ws + ((size_t)4 << 20));  // 4 MiB
  ushort_t* Vt = (ushort_t*)(ws + ((size_t)8 << 20));  // 8 MiB
  const size_t accsz = (size_t)NQ * DV * sizeof(_Float16);  // 8 MiB per split
  const size_t base = (size_t)16 << 20;

  int ks = 4;
  if (ws_size < base + 4 * (accsz + NQ * sizeof(float))) ks = 2;
  _Float16* pacc = (_Float16*)(ws + base);
  float* pdenom = (float*)(ws + base + (size_t)ks * accsz);

  hipLaunchKernelGGL(pre_kernel, dim3(2048), dim3(256), 0, stream,
                     img, text, Wq, Wk, Qh, Kh, Vt);
  hipLaunchKernelGGL(attn_kernel, dim3(128 * ks), dim3(256),
                     20480 * sizeof(ushort_t), stream,
                     Qh, Kh, Vt, pacc, pdenom, NQ / ks, ks);
  hipLaunchKernelGGL(combine_kernel, dim3((NQ * DV / 4) / 256), dim3(256), 0, stream,
                     pacc, pdenom, out, ks);
}